// Round 2
// baseline (4998.631 us; speedup 1.0000x reference)
//
#include <hip/hip_runtime.h>
#include <hip/hip_bf16.h>

typedef unsigned short u16b;

__device__ __forceinline__ float b2f(u16b u) { return __uint_as_float(((unsigned)u) << 16); }
__device__ __forceinline__ u16b f2b(float f) {
    unsigned u = __float_as_uint(f);
    unsigned r = u + 0x7fffu + ((u >> 16) & 1u);
    return (u16b)(r >> 16);
}

#define BATCH 4096
#define NPROJ 1920   /* 1800 valid cols + 120 zero pad */

// ---------------- pack W: [WQ|WK|WV|WQ2|WK2|WV2] -> wcat[300][1920] ----------------
__global__ void pack_wcat(const float* __restrict__ WQ, const float* __restrict__ WK,
                          const float* __restrict__ WV, const float* __restrict__ WQ2,
                          const float* __restrict__ WK2, const float* __restrict__ WV2,
                          float* __restrict__ wcat) {
    int idx = blockIdx.x * 256 + threadIdx.x;
    if (idx >= 300 * 1920) return;
    int k = idx / 1920, n = idx % 1920;
    float v;
    if      (n < 400)  v = WQ [k * 400 + n];
    else if (n < 800)  v = WK [k * 400 + (n - 400)];
    else if (n < 1200) v = WV [k * 400 + (n - 800)];
    else if (n < 1400) v = WQ2[k * 200 + (n - 1200)];
    else if (n < 1600) v = WK2[k * 200 + (n - 1400)];
    else if (n < 1800) v = WV2[k * 200 + (n - 1600)];
    else               v = 0.0f;
    wcat[idx] = v;
}

// ---------------- gather-fused projection GEMM ----------------
// C[m, 0..1919] (bf16) = table[ids[m]][0..299] @ wcat[300][1920]
// tile 64x128, 256 thr (16x16), 4x8 acc, BK=20 (300 = 15*20)
__global__ __launch_bounds__(256) void gemm_proj(const int* __restrict__ ids,
                                                 const float* __restrict__ table,
                                                 const float* __restrict__ wcat,
                                                 u16b* __restrict__ Out) {
    __shared__ float As[20][64];
    __shared__ float Bs[20][128];
    __shared__ int rowid[64];
    const int t  = threadIdx.x;
    const int n0 = blockIdx.x * 128;
    const int m0 = blockIdx.y * 64;
    if (t < 64) rowid[t] = ids[m0 + t];
    __syncthreads();
    const int r = t >> 2, k0 = (t & 3) * 5;       // A-load: 4 thr/row, 5 elems each
    const int bn = t & 127, bks = t >> 7;         // B-load
    const int ty = t >> 4, tx = t & 15;
    float acc[4][8] = {};
    for (int ks = 0; ks < 300; ks += 20) {
        float av[5];
        const float* arow = table + (long long)rowid[r] * 300 + ks + k0;
        #pragma unroll
        for (int i = 0; i < 5; i++) av[i] = arow[i];
        float bv[10];
        #pragma unroll
        for (int i = 0; i < 10; i++) bv[i] = wcat[(ks + i * 2 + bks) * NPROJ + n0 + bn];
        __syncthreads();
        #pragma unroll
        for (int i = 0; i < 5; i++) As[k0 + i][r] = av[i];
        #pragma unroll
        for (int i = 0; i < 10; i++) Bs[i * 2 + bks][bn] = bv[i];
        __syncthreads();
        #pragma unroll
        for (int kk = 0; kk < 20; kk++) {
            const float4 a4  = *(const float4*)(&As[kk][ty * 4]);
            const float4 b4a = *(const float4*)(&Bs[kk][tx * 4]);
            const float4 b4b = *(const float4*)(&Bs[kk][tx * 4 + 64]);
            const float aa[4] = {a4.x, a4.y, a4.z, a4.w};
            const float bb[8] = {b4a.x, b4a.y, b4a.z, b4a.w, b4b.x, b4b.y, b4b.z, b4b.w};
            #pragma unroll
            for (int i = 0; i < 4; i++)
                #pragma unroll
                for (int j = 0; j < 8; j++) acc[i][j] = fmaf(aa[i], bb[j], acc[i][j]);
        }
    }
    #pragma unroll
    for (int i = 0; i < 4; i++) {
        long long orow = (long long)(m0 + ty * 4 + i) * NPROJ;
        #pragma unroll
        for (int j = 0; j < 8; j++) {
            int nn = n0 + ((j < 4) ? (tx * 4 + j) : (64 + tx * 4 + j - 4));
            Out[orow + nn] = f2b(acc[i][j]);
        }
    }
}

// ---------------- dense GEMM: Out[m,n](bf16) = A(bf16)[m,K] @ W(f32)[K,N] + bias, opt tanh ----------------
__global__ __launch_bounds__(256) void gemm_dense(const u16b* __restrict__ A, int lda,
                                                  const float* __restrict__ W,
                                                  const float* __restrict__ Bias,
                                                  u16b* __restrict__ Out, int ldo,
                                                  int K, int N, int do_tanh) {
    __shared__ float As[20][64];
    __shared__ float Bs[20][128];
    const int t  = threadIdx.x;
    const int n0 = blockIdx.x * 128;
    const int m0 = blockIdx.y * 64;
    const int r = t >> 2, k0 = (t & 3) * 5;
    const int bn = t & 127, bks = t >> 7;
    const int ty = t >> 4, tx = t & 15;
    float acc[4][8] = {};
    for (int ks = 0; ks < K; ks += 20) {
        float av[5];
        const u16b* arow = A + (long long)(m0 + r) * lda + ks + k0;
        #pragma unroll
        for (int i = 0; i < 5; i++) av[i] = b2f(arow[i]);
        float bv[10];
        const int nn = n0 + bn;
        #pragma unroll
        for (int i = 0; i < 10; i++)
            bv[i] = (nn < N) ? W[(ks + i * 2 + bks) * N + nn] : 0.0f;
        __syncthreads();
        #pragma unroll
        for (int i = 0; i < 5; i++) As[k0 + i][r] = av[i];
        #pragma unroll
        for (int i = 0; i < 10; i++) Bs[i * 2 + bks][bn] = bv[i];
        __syncthreads();
        #pragma unroll
        for (int kk = 0; kk < 20; kk++) {
            const float4 a4  = *(const float4*)(&As[kk][ty * 4]);
            const float4 b4a = *(const float4*)(&Bs[kk][tx * 4]);
            const float4 b4b = *(const float4*)(&Bs[kk][tx * 4 + 64]);
            const float aa[4] = {a4.x, a4.y, a4.z, a4.w};
            const float bb[8] = {b4a.x, b4a.y, b4a.z, b4a.w, b4b.x, b4b.y, b4b.z, b4b.w};
            #pragma unroll
            for (int i = 0; i < 4; i++)
                #pragma unroll
                for (int j = 0; j < 8; j++) acc[i][j] = fmaf(aa[i], bb[j], acc[i][j]);
        }
    }
    #pragma unroll
    for (int i = 0; i < 4; i++) {
        long long orow = (long long)(m0 + ty * 4 + i) * ldo;
        #pragma unroll
        for (int j = 0; j < 8; j++) {
            int nn = n0 + ((j < 4) ? (tx * 4 + j) : (64 + tx * 4 + j - 4));
            if (nn < N) {
                float v = acc[i][j] + Bias[nn];
                if (do_tanh) v = tanhf(v);
                Out[orow + nn] = f2b(v);
            }
        }
    }
}

// ---------------- fc3 GEMM: out[4096,400](f32) = [tvec|evec|vert] @ fc3_W + b ----------------
__global__ __launch_bounds__(256) void gemm_fc3(const float* __restrict__ tvec,
                                                const float* __restrict__ evec,
                                                const float* __restrict__ vtab,
                                                const int* __restrict__ vids,
                                                const float* __restrict__ W,
                                                const float* __restrict__ Bias,
                                                float* __restrict__ Out) {
    __shared__ float As[20][64];
    __shared__ float Bs[20][128];
    __shared__ int svid[64];
    const int t  = threadIdx.x;
    const int n0 = blockIdx.x * 128;
    const int m0 = blockIdx.y * 64;
    if (t < 64) svid[t] = vids[m0 + t];
    __syncthreads();
    const int r = t >> 2, k0 = (t & 3) * 5;
    const int bn = t & 127, bks = t >> 7;
    const int ty = t >> 4, tx = t & 15;
    float acc[4][8] = {};
    const int rr = m0 + r;
    for (int ks = 0; ks < 1000; ks += 20) {
        float av[5];
        #pragma unroll
        for (int i = 0; i < 5; i++) {
            int k = ks + k0 + i;
            float a;
            if (k < 400)      a = tvec[rr * 400 + k];
            else if (k < 800) a = evec[rr * 400 + (k - 400)];
            else              a = vtab[svid[r] * 200 + (k - 800)];
            av[i] = a;
        }
        float bv[10];
        const int nn = n0 + bn;
        #pragma unroll
        for (int i = 0; i < 10; i++)
            bv[i] = (nn < 400) ? W[(ks + i * 2 + bks) * 400 + nn] : 0.0f;
        __syncthreads();
        #pragma unroll
        for (int i = 0; i < 5; i++) As[k0 + i][r] = av[i];
        #pragma unroll
        for (int i = 0; i < 10; i++) Bs[i * 2 + bks][bn] = bv[i];
        __syncthreads();
        #pragma unroll
        for (int kk = 0; kk < 20; kk++) {
            const float4 a4  = *(const float4*)(&As[kk][ty * 4]);
            const float4 b4a = *(const float4*)(&Bs[kk][tx * 4]);
            const float4 b4b = *(const float4*)(&Bs[kk][tx * 4 + 64]);
            const float aa[4] = {a4.x, a4.y, a4.z, a4.w};
            const float bb[8] = {b4a.x, b4a.y, b4a.z, b4a.w, b4b.x, b4b.y, b4b.z, b4b.w};
            #pragma unroll
            for (int i = 0; i < 4; i++)
                #pragma unroll
                for (int j = 0; j < 8; j++) acc[i][j] = fmaf(aa[i], bb[j], acc[i][j]);
        }
    }
    #pragma unroll
    for (int i = 0; i < 4; i++) {
        long long orow = (long long)(m0 + ty * 4 + i) * 400;
        #pragma unroll
        for (int j = 0; j < 8; j++) {
            int nn = n0 + ((j < 4) ? (tx * 4 + j) : (64 + tx * 4 + j - 4));
            if (nn < 400) Out[orow + nn] = acc[i][j] + Bias[nn];
        }
    }
}

// ---------------- title attention: self MHA(20,20) + co MHA(5,40) -> Tcat[C,30,600] ----------------
// Tproj row layout: [Q1:0..399 | K1:400..799 | V1:800..1199 | Q2:1200..1399 | K2:1400..1599 | V2:1600..1799]
__global__ __launch_bounds__(256) void attn_title(const u16b* __restrict__ Tproj,
                                                  const u16b* __restrict__ Eproj,
                                                  u16b* __restrict__ Tcat) {
    __shared__ u16b sm[24000];   // phase1: K1 (30x400) @0, V1 @12000; phase2: K2 (10x200) @0, V2 @2000
    const int b = blockIdx.x, t = threadIdx.x;
    // ---- phase 1: self attention
    for (int idx = t; idx < 12000; idx += 256) {
        int i = idx / 400, c = idx % 400;
        long long base = (long long)(b * 30 + i) * NPROJ;
        sm[idx]         = Tproj[base + 400 + c];
        sm[12000 + idx] = Tproj[base + 800 + c];
    }
    __syncthreads();
    const float scale1 = 0.22360679774997896f;  // 1/sqrt(20)
    for (int row = t; row < 600; row += 256) {
        int h = row / 30, i = row % 30;
        float q[20];
        const u16b* qrow = Tproj + (long long)(b * 30 + i) * NPROJ + h * 20;
        #pragma unroll
        for (int c = 0; c < 20; c++) q[c] = b2f(qrow[c]);
        float s[30];
        float mx = -1e30f;
        #pragma unroll
        for (int j = 0; j < 30; j++) {
            float a = 0.0f;
            #pragma unroll
            for (int c = 0; c < 20; c++) a += q[c] * b2f(sm[j * 400 + h * 20 + c]);
            s[j] = a * scale1;
            mx = fmaxf(mx, s[j]);
        }
        float sum = 0.0f;
        #pragma unroll
        for (int j = 0; j < 30; j++) { s[j] = __expf(s[j] - mx); sum += s[j]; }
        float inv = 1.0f / sum;
        #pragma unroll
        for (int c = 0; c < 20; c++) {
            float o = 0.0f;
            #pragma unroll
            for (int j = 0; j < 30; j++) o += s[j] * b2f(sm[12000 + j * 400 + h * 20 + c]);
            Tcat[(long long)(b * 30 + i) * 600 + h * 20 + c] = f2b(o * inv);
        }
    }
    __syncthreads();
    // ---- phase 2: co attention (queries=title, keys/values=entity)
    for (int idx = t; idx < 2000; idx += 256) {
        int j = idx / 200, c = idx % 200;
        long long base = (long long)(b * 10 + j) * NPROJ;
        sm[idx]        = Eproj[base + 1400 + c];
        sm[2000 + idx] = Eproj[base + 1600 + c];
    }
    __syncthreads();
    const float scale2 = 0.15811388300841897f;  // 1/sqrt(40)
    if (t < 150) {
        int h = t / 30, i = t % 30;
        float q[40];
        const u16b* qrow = Tproj + (long long)(b * 30 + i) * NPROJ + 1200 + h * 40;
        #pragma unroll
        for (int c = 0; c < 40; c++) q[c] = b2f(qrow[c]);
        float s[10];
        float mx = -1e30f;
        #pragma unroll
        for (int j = 0; j < 10; j++) {
            float a = 0.0f;
            #pragma unroll
            for (int c = 0; c < 40; c++) a += q[c] * b2f(sm[j * 200 + h * 40 + c]);
            s[j] = a * scale2;
            mx = fmaxf(mx, s[j]);
        }
        float sum = 0.0f;
        #pragma unroll
        for (int j = 0; j < 10; j++) { s[j] = __expf(s[j] - mx); sum += s[j]; }
        float inv = 1.0f / sum;
        #pragma unroll
        for (int c = 0; c < 40; c++) {
            float o = 0.0f;
            #pragma unroll
            for (int j = 0; j < 10; j++) o += s[j] * b2f(sm[2000 + j * 200 + h * 40 + c]);
            Tcat[(long long)(b * 30 + i) * 600 + 400 + h * 40 + c] = f2b(o * inv);
        }
    }
}

// ---------------- entity attention: self MHA(20,20) + co MHA(5,40, keys=title) -> Ecat[C,10,600] ----------------
__global__ __launch_bounds__(256) void attn_entity(const u16b* __restrict__ Tproj,
                                                   const u16b* __restrict__ Eproj,
                                                   u16b* __restrict__ Ecat) {
    __shared__ u16b sm[12000];   // phase1: K1 (10x400) @0, V1 @4000 ; phase2: K2 (30x200) @0, V2 @6000
    const int b = blockIdx.x, t = threadIdx.x;
    // ---- phase 1: self
    for (int idx = t; idx < 4000; idx += 256) {
        int i = idx / 400, c = idx % 400;
        long long base = (long long)(b * 10 + i) * NPROJ;
        sm[idx]        = Eproj[base + 400 + c];
        sm[4000 + idx] = Eproj[base + 800 + c];
    }
    __syncthreads();
    const float scale1 = 0.22360679774997896f;
    if (t < 200) {
        int h = t / 10, i = t % 10;
        float q[20];
        const u16b* qrow = Eproj + (long long)(b * 10 + i) * NPROJ + h * 20;
        #pragma unroll
        for (int c = 0; c < 20; c++) q[c] = b2f(qrow[c]);
        float s[10];
        float mx = -1e30f;
        #pragma unroll
        for (int j = 0; j < 10; j++) {
            float a = 0.0f;
            #pragma unroll
            for (int c = 0; c < 20; c++) a += q[c] * b2f(sm[j * 400 + h * 20 + c]);
            s[j] = a * scale1;
            mx = fmaxf(mx, s[j]);
        }
        float sum = 0.0f;
        #pragma unroll
        for (int j = 0; j < 10; j++) { s[j] = __expf(s[j] - mx); sum += s[j]; }
        float inv = 1.0f / sum;
        #pragma unroll
        for (int c = 0; c < 20; c++) {
            float o = 0.0f;
            #pragma unroll
            for (int j = 0; j < 10; j++) o += s[j] * b2f(sm[4000 + j * 400 + h * 20 + c]);
            Ecat[(long long)(b * 10 + i) * 600 + h * 20 + c] = f2b(o * inv);
        }
    }
    __syncthreads();
    // ---- phase 2: co (queries=entity, keys/values=title)
    for (int idx = t; idx < 6000; idx += 256) {
        int j = idx / 200, c = idx % 200;
        long long base = (long long)(b * 30 + j) * NPROJ;
        sm[idx]        = Tproj[base + 1400 + c];
        sm[6000 + idx] = Tproj[base + 1600 + c];
    }
    __syncthreads();
    const float scale2 = 0.15811388300841897f;
    if (t < 50) {
        int h = t / 10, i = t % 10;
        float q[40];
        const u16b* qrow = Eproj + (long long)(b * 10 + i) * NPROJ + 1200 + h * 40;
        #pragma unroll
        for (int c = 0; c < 40; c++) q[c] = b2f(qrow[c]);
        float s[30];
        float mx = -1e30f;
        #pragma unroll
        for (int j = 0; j < 30; j++) {
            float a = 0.0f;
            #pragma unroll
            for (int c = 0; c < 40; c++) a += q[c] * b2f(sm[j * 200 + h * 40 + c]);
            s[j] = a * scale2;
            mx = fmaxf(mx, s[j]);
        }
        float sum = 0.0f;
        #pragma unroll
        for (int j = 0; j < 30; j++) { s[j] = __expf(s[j] - mx); sum += s[j]; }
        float inv = 1.0f / sum;
        #pragma unroll
        for (int c = 0; c < 40; c++) {
            float o = 0.0f;
            #pragma unroll
            for (int j = 0; j < 30; j++) o += s[j] * b2f(sm[6000 + j * 200 + h * 40 + c]);
            Ecat[(long long)(b * 10 + i) * 600 + 400 + h * 40 + c] = f2b(o * inv);
        }
    }
}

// ---------------- attention pooling finalize ----------------
template <int L>
__global__ __launch_bounds__(256) void pool_finalize(const u16b* __restrict__ P,
                                                     const u16b* __restrict__ Vv,
                                                     const float* __restrict__ w2,
                                                     float* __restrict__ outv) {
    __shared__ float sred[L][8];
    __shared__ float sa[L];
    const int b = blockIdx.x, t = threadIdx.x;
    const int i = t / 8, u = t % 8;
    if (i < L) {
        float p = 0.0f;
        const u16b* Pr = P + (long long)(b * L + i) * 200 + u * 25;
        const float* wr = w2 + u * 25;
        #pragma unroll
        for (int c = 0; c < 25; c++) p += b2f(Pr[c]) * wr[c];
        sred[i][u] = p;
    }
    __syncthreads();
    if (t == 0) {
        float s[L];
        float mx = -1e30f;
        for (int ii = 0; ii < L; ii++) {
            float v = 0.0f;
            for (int uu = 0; uu < 8; uu++) v += sred[ii][uu];
            s[ii] = v;
            mx = fmaxf(mx, v);
        }
        float sum = 0.0f;
        for (int ii = 0; ii < L; ii++) { s[ii] = __expf(s[ii] - mx); sum += s[ii]; }
        float inv = 1.0f / sum;
        for (int ii = 0; ii < L; ii++) sa[ii] = s[ii] * inv;
    }
    __syncthreads();
    for (int f = t; f < 400; f += 256) {
        float o = 0.0f;
        #pragma unroll
        for (int ii = 0; ii < L; ii++) o += sa[ii] * b2f(Vv[(long long)(b * L + ii) * 400 + f]);
        outv[(long long)b * 400 + f] = o;
    }
}

extern "C" void kernel_launch(void* const* d_in, const int* in_sizes, int n_in,
                              void* d_out, int out_size, void* d_ws, size_t ws_size,
                              hipStream_t stream) {
    const int*   title_ids  = (const int*)d_in[0];
    const int*   vert_ids   = (const int*)d_in[1];
    const int*   entity_ids = (const int*)d_in[2];
    const float* word_table = (const float*)d_in[3];
    const float* vert_table = (const float*)d_in[4];
    const float* entity_table = (const float*)d_in[5];
    const float* WQ  = (const float*)d_in[6];
    const float* WK  = (const float*)d_in[7];
    const float* WV  = (const float*)d_in[8];
    const float* WQ2 = (const float*)d_in[9];
    const float* WK2 = (const float*)d_in[10];
    const float* WV2 = (const float*)d_in[11];
    const float* fc1_W = (const float*)d_in[12];
    const float* fc1_b = (const float*)d_in[13];
    const float* fc2_W = (const float*)d_in[14];
    const float* fc2_b = (const float*)d_in[15];
    const float* apt_W1 = (const float*)d_in[16];
    const float* apt_b1 = (const float*)d_in[17];
    const float* apt_w2 = (const float*)d_in[18];
    const float* ape_W1 = (const float*)d_in[19];
    const float* ape_b1 = (const float*)d_in[20];
    const float* ape_w2 = (const float*)d_in[21];
    const float* fc3_W = (const float*)d_in[22];
    const float* fc3_b = (const float*)d_in[23];

    // ---- ws-adaptive chunking: need(C) = fixed + C*201600 bytes ----
    // per-sample: Tproj 30*1920*2=115200, Eproj 10*1920*2=38400,
    //             Tcat 30*600*2=36000,  Ecat 10*600*2=12000   -> 201600 B
    const long long fixedB = 2304000ll /*wcat*/ + 2ll * 6553600ll /*tvec+evec f32*/;
    int C = BATCH;
    while (C > 32 && fixedB + (long long)C * 201600ll > (long long)ws_size) C >>= 1;

    char* ws = (char*)d_ws;
    const long long OFF_WCAT  = 0;
    const long long OFF_TVEC  = 2304000ll;
    const long long OFF_EVEC  = OFF_TVEC + 6553600ll;
    const long long OFF_TPROJ = OFF_EVEC + 6553600ll;
    const long long OFF_EPROJ = OFF_TPROJ + (long long)C * 115200ll;
    const long long OFF_TCAT  = OFF_EPROJ + (long long)C * 38400ll;
    const long long OFF_ECAT  = OFF_TCAT  + (long long)C * 36000ll;
    // overlays (dead-region reuse within a chunk):
    const long long OFF_TV = OFF_TPROJ;                          // C*30*400*2 = C*24000
    const long long OFF_EV = OFF_TPROJ + (long long)C * 24000ll; // C*10*400*2 = C*8000
    const long long OFF_PT = OFF_EPROJ;                          // C*30*200*2 = C*12000
    const long long OFF_PE = OFF_EPROJ + (long long)C * 12000ll; // C*10*200*2 = C*4000

    float* wcat  = (float*)(ws + OFF_WCAT);
    u16b*  Tproj = (u16b*)(ws + OFF_TPROJ);
    u16b*  Eproj = (u16b*)(ws + OFF_EPROJ);
    u16b*  Tcat  = (u16b*)(ws + OFF_TCAT);
    u16b*  Ecat  = (u16b*)(ws + OFF_ECAT);
    float* tvec  = (float*)(ws + OFF_TVEC);
    float* evec  = (float*)(ws + OFF_EVEC);
    u16b*  Tv    = (u16b*)(ws + OFF_TV);
    u16b*  Ev    = (u16b*)(ws + OFF_EV);
    u16b*  Pt    = (u16b*)(ws + OFF_PT);
    u16b*  Pe    = (u16b*)(ws + OFF_PE);
    float* outp  = (float*)d_out;

    // 1. pack concatenated projection weights (zero-padded to 1920 cols)
    pack_wcat<<<(300 * 1920 + 255) / 256, 256, 0, stream>>>(WQ, WK, WV, WQ2, WK2, WV2, wcat);

    for (int c0 = 0; c0 < BATCH; c0 += C) {
        const int mT = C * 30 / 64;   // title-row tiles   (C>=32 -> integer)
        const int mE = C * 10 / 64;   // entity-row tiles
        // 2. projections (gather fused)
        gemm_proj<<<dim3(15, mT), 256, 0, stream>>>(title_ids + (long long)c0 * 30, word_table, wcat, Tproj);
        gemm_proj<<<dim3(15, mE), 256, 0, stream>>>(entity_ids + (long long)c0 * 10, entity_table, wcat, Eproj);
        // 3. attention (self + co)
        attn_title<<<C, 256, 0, stream>>>(Tproj, Eproj, Tcat);
        attn_entity<<<C, 256, 0, stream>>>(Tproj, Eproj, Ecat);
        // 4. fc1 / fc2 (Tv/Ev overlay Tproj; projections dead now)
        gemm_dense<<<dim3(4, mT), 256, 0, stream>>>(Tcat, 600, fc1_W, fc1_b, Tv, 400, 600, 400, 0);
        gemm_dense<<<dim3(4, mE), 256, 0, stream>>>(Ecat, 600, fc2_W, fc2_b, Ev, 400, 600, 400, 0);
        // 5. pooling score GEMMs: P = tanh(x @ W1 + b1)  (Pt/Pe overlay Eproj)
        gemm_dense<<<dim3(2, mT), 256, 0, stream>>>(Tv, 400, apt_W1, apt_b1, Pt, 200, 400, 200, 1);
        gemm_dense<<<dim3(2, mE), 256, 0, stream>>>(Ev, 400, ape_W1, ape_b1, Pe, 200, 400, 200, 1);
        // 6. pooling finalize -> tvec/evec slices (f32, full-batch persistent)
        pool_finalize<30><<<C, 256, 0, stream>>>(Pt, Tv, apt_w2, tvec + (long long)c0 * 400);
        pool_finalize<10><<<C, 256, 0, stream>>>(Pe, Ev, ape_w2, evec + (long long)c0 * 400);
    }
    // 7. fc3 on [tvec | evec | vert_vec]
    gemm_fc3<<<dim3(4, BATCH / 64), 256, 0, stream>>>(tvec, evec, vert_table, vert_ids, fc3_W, fc3_b, outp);
}

// Round 3
// 2893.756 us; speedup vs baseline: 1.7274x; 1.7274x over previous
//
#include <hip/hip_runtime.h>
#include <hip/hip_bf16.h>

typedef unsigned short u16b;
typedef __attribute__((ext_vector_type(8))) short bf16x8;
typedef __attribute__((ext_vector_type(4))) float f32x4;

__device__ __forceinline__ float b2f(u16b u) { return __uint_as_float(((unsigned)u) << 16); }
__device__ __forceinline__ u16b f2b(float f) {
    unsigned u = __float_as_uint(f);
    unsigned r = u + 0x7fffu + ((u >> 16) & 1u);
    return (u16b)(r >> 16);
}
__device__ __forceinline__ int pk2(float a, float b) {
    return (int)f2b(a) | ((int)f2b(b) << 16);
}

#define BATCH 4096
#define NPROJ 1920   /* proj out stride; cols 0..1799 valid */

// ================= weight pack kernels (f32 -> bf16, transposed, K zero-padded) =================
// wcatT[1800][320]: n in [0,1800) maps to [WQ|WK|WV|WQ2|WK2|WV2] col, k in [0,320), zero for k>=300
__global__ void pack_wcatT(const float* __restrict__ WQ, const float* __restrict__ WK,
                           const float* __restrict__ WV, const float* __restrict__ WQ2,
                           const float* __restrict__ WK2, const float* __restrict__ WV2,
                           u16b* __restrict__ Wt) {
    int idx = blockIdx.x * 256 + threadIdx.x;
    if (idx >= 1800 * 320) return;
    int n = idx / 320, k = idx % 320;
    float v = 0.0f;
    if (k < 300) {
        if      (n < 400)  v = WQ [k * 400 + n];
        else if (n < 800)  v = WK [k * 400 + (n - 400)];
        else if (n < 1200) v = WV [k * 400 + (n - 800)];
        else if (n < 1400) v = WQ2[k * 200 + (n - 1200)];
        else if (n < 1600) v = WK2[k * 200 + (n - 1400)];
        else               v = WV2[k * 200 + (n - 1600)];
    }
    Wt[idx] = f2b(v);
}

// generic: W[K][N] f32 -> Wt[N][Kp] bf16 (zero pad k>=K)
__global__ void pack_wt(const float* __restrict__ W, u16b* __restrict__ Wt,
                        int K, int N, int Kp) {
    int idx = blockIdx.x * 256 + threadIdx.x;
    if (idx >= N * Kp) return;
    int n = idx / Kp, k = idx % Kp;
    Wt[idx] = f2b((k < K) ? W[k * N + n] : 0.0f);
}

// ================= MFMA GEMM =================
// Out[M,N](bf16) = A[M,K] @ Wt^T + bias (opt tanh)
// A: bf16 dense (stride lda) or f32 gather rows table[ids[m]] (stride lda=300)
// Wt: [N][ldwt] bf16, zero-padded to >= kiters*32
// tile 128x128, 256 thr = 4 waves, wave = 64x64 via 4x4 of mfma_f32_16x16x32_bf16
template<int GATHER, int HAS_BIAS, int DO_TANH>
__global__ __launch_bounds__(256) void gemm_mfma(
        const u16b* __restrict__ A, long long lda, int K,
        const int* __restrict__ ids, const float* __restrict__ table,
        const u16b* __restrict__ Wt, int ldwt,
        const float* __restrict__ Bias,
        u16b* __restrict__ Out, long long ldo, int M, int N) {
    __shared__ __align__(16) u16b As[128 * 32];
    __shared__ __align__(16) u16b Bs[128 * 32];
    __shared__ int rowid[128];

    const int t = threadIdx.x;
    const int lane = t & 63;
    const int wave = t >> 6;
    const int wm = wave & 1, wn = wave >> 1;
    const int n0 = blockIdx.x * 128;
    const int m0 = blockIdx.y * 128;

    if (GATHER) {
        if (t < 128) {
            int m = m0 + t;
            rowid[t] = (m < M) ? ids[m] : 0;
        }
        __syncthreads();
    }

    // staging map: thread t handles chunks {row=cr, row=cr+64} x 8 bf16 at k-offset ck
    const int cr = t >> 2;
    const int ck = (t & 3) * 8;

    f32x4 acc[4][4];
    const f32x4 zf = {0.f, 0.f, 0.f, 0.f};
    #pragma unroll
    for (int mi = 0; mi < 4; mi++)
        #pragma unroll
        for (int ni = 0; ni < 4; ni++) acc[mi][ni] = zf;

    const int kiters = (K + 31) >> 5;
    for (int it = 0; it < kiters; ++it) {
        const int k0 = it * 32;
        const int kc = k0 + ck;
        int4 av[2], bv[2];
        #pragma unroll
        for (int h = 0; h < 2; h++) {
            const int row = cr + h * 64;
            const int m = m0 + row;
            // ---- A chunk
            if (GATHER) {
                const float* grow = table + (long long)rowid[row] * lda;
                if (m < M && kc + 8 <= K) {
                    float4 f0 = *(const float4*)(grow + kc);
                    float4 f1 = *(const float4*)(grow + kc + 4);
                    av[h].x = pk2(f0.x, f0.y); av[h].y = pk2(f0.z, f0.w);
                    av[h].z = pk2(f1.x, f1.y); av[h].w = pk2(f1.z, f1.w);
                } else if (m < M && kc < K) {
                    float fv[8];
                    #pragma unroll
                    for (int i = 0; i < 8; i++) fv[i] = (kc + i < K) ? grow[kc + i] : 0.0f;
                    av[h].x = pk2(fv[0], fv[1]); av[h].y = pk2(fv[2], fv[3]);
                    av[h].z = pk2(fv[4], fv[5]); av[h].w = pk2(fv[6], fv[7]);
                } else {
                    av[h].x = av[h].y = av[h].z = av[h].w = 0;
                }
            } else {
                const u16b* drow = A + (long long)m * lda;
                if (m < M && kc + 8 <= K) {
                    av[h] = *(const int4*)(drow + kc);
                } else if (m < M && kc < K) {
                    u16b tv[8];
                    #pragma unroll
                    for (int i = 0; i < 8; i++) tv[i] = (kc + i < K) ? drow[kc + i] : (u16b)0;
                    av[h].x = (int)tv[0] | ((int)tv[1] << 16);
                    av[h].y = (int)tv[2] | ((int)tv[3] << 16);
                    av[h].z = (int)tv[4] | ((int)tv[5] << 16);
                    av[h].w = (int)tv[6] | ((int)tv[7] << 16);
                } else {
                    av[h].x = av[h].y = av[h].z = av[h].w = 0;
                }
            }
            // ---- B chunk (Wt padded in k, predicate only on n)
            const int n = n0 + row;
            if (n < N) {
                bv[h] = *(const int4*)(Wt + (long long)n * ldwt + kc);
            } else {
                bv[h].x = bv[h].y = bv[h].z = bv[h].w = 0;
            }
        }
        __syncthreads();
        *(int4*)(&As[cr * 32 + ck])        = av[0];
        *(int4*)(&As[(cr + 64) * 32 + ck]) = av[1];
        *(int4*)(&Bs[cr * 32 + ck])        = bv[0];
        *(int4*)(&Bs[(cr + 64) * 32 + ck]) = bv[1];
        __syncthreads();

        bf16x8 af[4], bf[4];
        const int lr = lane & 15;
        const int kq = (lane >> 4) * 8;
        #pragma unroll
        for (int mi = 0; mi < 4; mi++)
            af[mi] = *(const bf16x8*)(&As[(wm * 64 + mi * 16 + lr) * 32 + kq]);
        #pragma unroll
        for (int ni = 0; ni < 4; ni++)
            bf[ni] = *(const bf16x8*)(&Bs[(wn * 64 + ni * 16 + lr) * 32 + kq]);
        #pragma unroll
        for (int mi = 0; mi < 4; mi++)
            #pragma unroll
            for (int ni = 0; ni < 4; ni++)
                acc[mi][ni] = __builtin_amdgcn_mfma_f32_16x16x32_bf16(af[mi], bf[ni], acc[mi][ni], 0, 0, 0);
    }

    // epilogue: C/D layout col=lane&15, row=(lane>>4)*4+r
    const int cl = lane & 15;
    const int rb = (lane >> 4) * 4;
    #pragma unroll
    for (int ni = 0; ni < 4; ni++) {
        const int col = n0 + wn * 64 + ni * 16 + cl;
        if (col >= N) continue;
        const float bias = HAS_BIAS ? Bias[col] : 0.0f;
        #pragma unroll
        for (int mi = 0; mi < 4; mi++) {
            #pragma unroll
            for (int r = 0; r < 4; r++) {
                const int row = m0 + wm * 64 + mi * 16 + rb + r;
                if (row < M) {
                    float v = acc[mi][ni][r] + bias;
                    if (DO_TANH) v = tanhf(v);
                    Out[(long long)row * ldo + col] = f2b(v);
                }
            }
        }
    }
}

// ---------------- fc3 GEMM: out[4096,400](f32) = [tvec|evec|vert] @ fc3_W + b ----------------
__global__ __launch_bounds__(256) void gemm_fc3(const float* __restrict__ tvec,
                                                const float* __restrict__ evec,
                                                const float* __restrict__ vtab,
                                                const int* __restrict__ vids,
                                                const float* __restrict__ W,
                                                const float* __restrict__ Bias,
                                                float* __restrict__ Out) {
    __shared__ float As[20][64];
    __shared__ float Bs[20][128];
    __shared__ int svid[64];
    const int t  = threadIdx.x;
    const int n0 = blockIdx.x * 128;
    const int m0 = blockIdx.y * 64;
    if (t < 64) svid[t] = vids[m0 + t];
    __syncthreads();
    const int r = t >> 2, k0 = (t & 3) * 5;
    const int bn = t & 127, bks = t >> 7;
    const int ty = t >> 4, tx = t & 15;
    float acc[4][8] = {};
    const int rr = m0 + r;
    for (int ks = 0; ks < 1000; ks += 20) {
        float av[5];
        #pragma unroll
        for (int i = 0; i < 5; i++) {
            int k = ks + k0 + i;
            float a;
            if (k < 400)      a = tvec[rr * 400 + k];
            else if (k < 800) a = evec[rr * 400 + (k - 400)];
            else              a = vtab[svid[r] * 200 + (k - 800)];
            av[i] = a;
        }
        float bv[10];
        const int nn = n0 + bn;
        #pragma unroll
        for (int i = 0; i < 10; i++)
            bv[i] = (nn < 400) ? W[(ks + i * 2 + bks) * 400 + nn] : 0.0f;
        __syncthreads();
        #pragma unroll
        for (int i = 0; i < 5; i++) As[k0 + i][r] = av[i];
        #pragma unroll
        for (int i = 0; i < 10; i++) Bs[i * 2 + bks][bn] = bv[i];
        __syncthreads();
        #pragma unroll
        for (int kk = 0; kk < 20; kk++) {
            const float4 a4  = *(const float4*)(&As[kk][ty * 4]);
            const float4 b4a = *(const float4*)(&Bs[kk][tx * 4]);
            const float4 b4b = *(const float4*)(&Bs[kk][tx * 4 + 64]);
            const float aa[4] = {a4.x, a4.y, a4.z, a4.w};
            const float bb[8] = {b4a.x, b4a.y, b4a.z, b4a.w, b4b.x, b4b.y, b4b.z, b4b.w};
            #pragma unroll
            for (int i = 0; i < 4; i++)
                #pragma unroll
                for (int j = 0; j < 8; j++) acc[i][j] = fmaf(aa[i], bb[j], acc[i][j]);
        }
    }
    #pragma unroll
    for (int i = 0; i < 4; i++) {
        long long orow = (long long)(m0 + ty * 4 + i) * 400;
        #pragma unroll
        for (int j = 0; j < 8; j++) {
            int nn = n0 + ((j < 4) ? (tx * 4 + j) : (64 + tx * 4 + j - 4));
            if (nn < 400) Out[orow + nn] = acc[i][j] + Bias[nn];
        }
    }
}

// ---------------- title attention: self MHA(20,20) + co MHA(5,40) -> Tcat[C,30,600] ----------------
// Tproj row layout: [Q1:0..399 | K1:400..799 | V1:800..1199 | Q2:1200..1399 | K2:1400..1599 | V2:1600..1799]
__global__ __launch_bounds__(256) void attn_title(const u16b* __restrict__ Tproj,
                                                  const u16b* __restrict__ Eproj,
                                                  u16b* __restrict__ Tcat) {
    __shared__ u16b sm[24000];
    const int b = blockIdx.x, t = threadIdx.x;
    for (int idx = t; idx < 12000; idx += 256) {
        int i = idx / 400, c = idx % 400;
        long long base = (long long)(b * 30 + i) * NPROJ;
        sm[idx]         = Tproj[base + 400 + c];
        sm[12000 + idx] = Tproj[base + 800 + c];
    }
    __syncthreads();
    const float scale1 = 0.22360679774997896f;
    for (int row = t; row < 600; row += 256) {
        int h = row / 30, i = row % 30;
        float q[20];
        const u16b* qrow = Tproj + (long long)(b * 30 + i) * NPROJ + h * 20;
        #pragma unroll
        for (int c = 0; c < 20; c++) q[c] = b2f(qrow[c]);
        float s[30];
        float mx = -1e30f;
        #pragma unroll
        for (int j = 0; j < 30; j++) {
            float a = 0.0f;
            #pragma unroll
            for (int c = 0; c < 20; c++) a += q[c] * b2f(sm[j * 400 + h * 20 + c]);
            s[j] = a * scale1;
            mx = fmaxf(mx, s[j]);
        }
        float sum = 0.0f;
        #pragma unroll
        for (int j = 0; j < 30; j++) { s[j] = __expf(s[j] - mx); sum += s[j]; }
        float inv = 1.0f / sum;
        #pragma unroll
        for (int c = 0; c < 20; c++) {
            float o = 0.0f;
            #pragma unroll
            for (int j = 0; j < 30; j++) o += s[j] * b2f(sm[12000 + j * 400 + h * 20 + c]);
            Tcat[(long long)(b * 30 + i) * 600 + h * 20 + c] = f2b(o * inv);
        }
    }
    __syncthreads();
    for (int idx = t; idx < 2000; idx += 256) {
        int j = idx / 200, c = idx % 200;
        long long base = (long long)(b * 10 + j) * NPROJ;
        sm[idx]        = Eproj[base + 1400 + c];
        sm[2000 + idx] = Eproj[base + 1600 + c];
    }
    __syncthreads();
    const float scale2 = 0.15811388300841897f;
    if (t < 150) {
        int h = t / 30, i = t % 30;
        float q[40];
        const u16b* qrow = Tproj + (long long)(b * 30 + i) * NPROJ + 1200 + h * 40;
        #pragma unroll
        for (int c = 0; c < 40; c++) q[c] = b2f(qrow[c]);
        float s[10];
        float mx = -1e30f;
        #pragma unroll
        for (int j = 0; j < 10; j++) {
            float a = 0.0f;
            #pragma unroll
            for (int c = 0; c < 40; c++) a += q[c] * b2f(sm[j * 200 + h * 40 + c]);
            s[j] = a * scale2;
            mx = fmaxf(mx, s[j]);
        }
        float sum = 0.0f;
        #pragma unroll
        for (int j = 0; j < 10; j++) { s[j] = __expf(s[j] - mx); sum += s[j]; }
        float inv = 1.0f / sum;
        #pragma unroll
        for (int c = 0; c < 40; c++) {
            float o = 0.0f;
            #pragma unroll
            for (int j = 0; j < 10; j++) o += s[j] * b2f(sm[2000 + j * 200 + h * 40 + c]);
            Tcat[(long long)(b * 30 + i) * 600 + 400 + h * 40 + c] = f2b(o * inv);
        }
    }
}

// ---------------- entity attention ----------------
__global__ __launch_bounds__(256) void attn_entity(const u16b* __restrict__ Tproj,
                                                   const u16b* __restrict__ Eproj,
                                                   u16b* __restrict__ Ecat) {
    __shared__ u16b sm[12000];
    const int b = blockIdx.x, t = threadIdx.x;
    for (int idx = t; idx < 4000; idx += 256) {
        int i = idx / 400, c = idx % 400;
        long long base = (long long)(b * 10 + i) * NPROJ;
        sm[idx]        = Eproj[base + 400 + c];
        sm[4000 + idx] = Eproj[base + 800 + c];
    }
    __syncthreads();
    const float scale1 = 0.22360679774997896f;
    if (t < 200) {
        int h = t / 10, i = t % 10;
        float q[20];
        const u16b* qrow = Eproj + (long long)(b * 10 + i) * NPROJ + h * 20;
        #pragma unroll
        for (int c = 0; c < 20; c++) q[c] = b2f(qrow[c]);
        float s[10];
        float mx = -1e30f;
        #pragma unroll
        for (int j = 0; j < 10; j++) {
            float a = 0.0f;
            #pragma unroll
            for (int c = 0; c < 20; c++) a += q[c] * b2f(sm[j * 400 + h * 20 + c]);
            s[j] = a * scale1;
            mx = fmaxf(mx, s[j]);
        }
        float sum = 0.0f;
        #pragma unroll
        for (int j = 0; j < 10; j++) { s[j] = __expf(s[j] - mx); sum += s[j]; }
        float inv = 1.0f / sum;
        #pragma unroll
        for (int c = 0; c < 20; c++) {
            float o = 0.0f;
            #pragma unroll
            for (int j = 0; j < 10; j++) o += s[j] * b2f(sm[4000 + j * 400 + h * 20 + c]);
            Ecat[(long long)(b * 10 + i) * 600 + h * 20 + c] = f2b(o * inv);
        }
    }
    __syncthreads();
    for (int idx = t; idx < 6000; idx += 256) {
        int j = idx / 200, c = idx % 200;
        long long base = (long long)(b * 30 + j) * NPROJ;
        sm[idx]        = Tproj[base + 1400 + c];
        sm[6000 + idx] = Tproj[base + 1600 + c];
    }
    __syncthreads();
    const float scale2 = 0.15811388300841897f;
    if (t < 50) {
        int h = t / 10, i = t % 10;
        float q[40];
        const u16b* qrow = Eproj + (long long)(b * 10 + i) * NPROJ + 1200 + h * 40;
        #pragma unroll
        for (int c = 0; c < 40; c++) q[c] = b2f(qrow[c]);
        float s[30];
        float mx = -1e30f;
        #pragma unroll
        for (int j = 0; j < 30; j++) {
            float a = 0.0f;
            #pragma unroll
            for (int c = 0; c < 40; c++) a += q[c] * b2f(sm[j * 200 + h * 40 + c]);
            s[j] = a * scale2;
            mx = fmaxf(mx, s[j]);
        }
        float sum = 0.0f;
        #pragma unroll
        for (int j = 0; j < 30; j++) { s[j] = __expf(s[j] - mx); sum += s[j]; }
        float inv = 1.0f / sum;
        #pragma unroll
        for (int c = 0; c < 40; c++) {
            float o = 0.0f;
            #pragma unroll
            for (int j = 0; j < 30; j++) o += s[j] * b2f(sm[6000 + j * 200 + h * 40 + c]);
            Ecat[(long long)(b * 10 + i) * 600 + 400 + h * 40 + c] = f2b(o * inv);
        }
    }
}

// ---------------- attention pooling finalize ----------------
template <int L>
__global__ __launch_bounds__(256) void pool_finalize(const u16b* __restrict__ P,
                                                     const u16b* __restrict__ Vv,
                                                     const float* __restrict__ w2,
                                                     float* __restrict__ outv) {
    __shared__ float sred[L][8];
    __shared__ float sa[L];
    const int b = blockIdx.x, t = threadIdx.x;
    const int i = t / 8, u = t % 8;
    if (i < L) {
        float p = 0.0f;
        const u16b* Pr = P + (long long)(b * L + i) * 200 + u * 25;
        const float* wr = w2 + u * 25;
        #pragma unroll
        for (int c = 0; c < 25; c++) p += b2f(Pr[c]) * wr[c];
        sred[i][u] = p;
    }
    __syncthreads();
    if (t == 0) {
        float s[L];
        float mx = -1e30f;
        for (int ii = 0; ii < L; ii++) {
            float v = 0.0f;
            for (int uu = 0; uu < 8; uu++) v += sred[ii][uu];
            s[ii] = v;
            mx = fmaxf(mx, v);
        }
        float sum = 0.0f;
        for (int ii = 0; ii < L; ii++) { s[ii] = __expf(s[ii] - mx); sum += s[ii]; }
        float inv = 1.0f / sum;
        for (int ii = 0; ii < L; ii++) sa[ii] = s[ii] * inv;
    }
    __syncthreads();
    for (int f = t; f < 400; f += 256) {
        float o = 0.0f;
        #pragma unroll
        for (int ii = 0; ii < L; ii++) o += sa[ii] * b2f(Vv[(long long)(b * L + ii) * 400 + f]);
        outv[(long long)b * 400 + f] = o;
    }
}

extern "C" void kernel_launch(void* const* d_in, const int* in_sizes, int n_in,
                              void* d_out, int out_size, void* d_ws, size_t ws_size,
                              hipStream_t stream) {
    const int*   title_ids  = (const int*)d_in[0];
    const int*   vert_ids   = (const int*)d_in[1];
    const int*   entity_ids = (const int*)d_in[2];
    const float* word_table = (const float*)d_in[3];
    const float* vert_table = (const float*)d_in[4];
    const float* entity_table = (const float*)d_in[5];
    const float* WQ  = (const float*)d_in[6];
    const float* WK  = (const float*)d_in[7];
    const float* WV  = (const float*)d_in[8];
    const float* WQ2 = (const float*)d_in[9];
    const float* WK2 = (const float*)d_in[10];
    const float* WV2 = (const float*)d_in[11];
    const float* fc1_W = (const float*)d_in[12];
    const float* fc1_b = (const float*)d_in[13];
    const float* fc2_W = (const float*)d_in[14];
    const float* fc2_b = (const float*)d_in[15];
    const float* apt_W1 = (const float*)d_in[16];
    const float* apt_b1 = (const float*)d_in[17];
    const float* apt_w2 = (const float*)d_in[18];
    const float* ape_W1 = (const float*)d_in[19];
    const float* ape_b1 = (const float*)d_in[20];
    const float* ape_w2 = (const float*)d_in[21];
    const float* fc3_W = (const float*)d_in[22];
    const float* fc3_b = (const float*)d_in[23];

    // fixed region: packed bf16 weights + tvec/evec (f32, full batch)
    const long long OFF_WCATT = 0;                               // 1800*320*2 = 1,152,000
    const long long OFF_FC1WT = 1152000ll;                       // 400*608*2  =   486,400
    const long long OFF_FC2WT = OFF_FC1WT + 486400ll;
    const long long OFF_APTWT = OFF_FC2WT + 486400ll;            // 200*416*2  =   166,400
    const long long OFF_APEWT = OFF_APTWT + 166400ll;
    const long long OFF_TVEC  = OFF_APEWT + 166400ll;            // 4096*400*4 = 6,553,600
    const long long OFF_EVEC  = OFF_TVEC + 6553600ll;
    const long long fixedB    = OFF_EVEC + 6553600ll;            // 15,564,800

    // per-chunk: Tproj C*30*1920*2 + Eproj C*10*1920*2 + Tcat C*30*600*2 + Ecat C*10*600*2
    int C = BATCH;
    while (C > 32 && fixedB + (long long)C * 201600ll > (long long)ws_size) C >>= 1;

    char* ws = (char*)d_ws;
    const long long OFF_TPROJ = fixedB;
    const long long OFF_EPROJ = OFF_TPROJ + (long long)C * 115200ll;
    const long long OFF_TCAT  = OFF_EPROJ + (long long)C * 38400ll;
    const long long OFF_ECAT  = OFF_TCAT  + (long long)C * 36000ll;
    // overlays (dead-region reuse within a chunk)
    const long long OFF_TV = OFF_TPROJ;
    const long long OFF_EV = OFF_TPROJ + (long long)C * 24000ll;
    const long long OFF_PT = OFF_EPROJ;
    const long long OFF_PE = OFF_EPROJ + (long long)C * 12000ll;

    u16b*  wcatT = (u16b*)(ws + OFF_WCATT);
    u16b*  fc1Wt = (u16b*)(ws + OFF_FC1WT);
    u16b*  fc2Wt = (u16b*)(ws + OFF_FC2WT);
    u16b*  aptWt = (u16b*)(ws + OFF_APTWT);
    u16b*  apeWt = (u16b*)(ws + OFF_APEWT);
    float* tvec  = (float*)(ws + OFF_TVEC);
    float* evec  = (float*)(ws + OFF_EVEC);
    u16b*  Tproj = (u16b*)(ws + OFF_TPROJ);
    u16b*  Eproj = (u16b*)(ws + OFF_EPROJ);
    u16b*  Tcat  = (u16b*)(ws + OFF_TCAT);
    u16b*  Ecat  = (u16b*)(ws + OFF_ECAT);
    u16b*  Tv    = (u16b*)(ws + OFF_TV);
    u16b*  Ev    = (u16b*)(ws + OFF_EV);
    u16b*  Pt    = (u16b*)(ws + OFF_PT);
    u16b*  Pe    = (u16b*)(ws + OFF_PE);
    float* outp  = (float*)d_out;

    // 1. pack bf16 transposed weights
    pack_wcatT<<<(1800 * 320 + 255) / 256, 256, 0, stream>>>(WQ, WK, WV, WQ2, WK2, WV2, wcatT);
    pack_wt<<<(400 * 608 + 255) / 256, 256, 0, stream>>>(fc1_W, fc1Wt, 600, 400, 608);
    pack_wt<<<(400 * 608 + 255) / 256, 256, 0, stream>>>(fc2_W, fc2Wt, 600, 400, 608);
    pack_wt<<<(200 * 416 + 255) / 256, 256, 0, stream>>>(apt_W1, aptWt, 400, 200, 416);
    pack_wt<<<(200 * 416 + 255) / 256, 256, 0, stream>>>(ape_W1, apeWt, 400, 200, 416);

    for (int c0 = 0; c0 < BATCH; c0 += C) {
        const int MT = C * 30, ME = C * 10;
        const int gT = (MT + 127) / 128, gE = (ME + 127) / 128;
        // 2. projections (gather + bf16 MFMA), N=1800 valid cols, out stride 1920
        gemm_mfma<1, 0, 0><<<dim3(15, gT), 256, 0, stream>>>(
            nullptr, 300, 300, title_ids + (long long)c0 * 30, word_table,
            wcatT, 320, nullptr, Tproj, NPROJ, MT, 1800);
        gemm_mfma<1, 0, 0><<<dim3(15, gE), 256, 0, stream>>>(
            nullptr, 300, 300, entity_ids + (long long)c0 * 10, entity_table,
            wcatT, 320, nullptr, Eproj, NPROJ, ME, 1800);
        // 3. attention (self + co)
        attn_title<<<C, 256, 0, stream>>>(Tproj, Eproj, Tcat);
        attn_entity<<<C, 256, 0, stream>>>(Tproj, Eproj, Ecat);
        // 4. fc1 / fc2 (Tv/Ev overlay Tproj; projections dead now)
        gemm_mfma<0, 1, 0><<<dim3(4, gT), 256, 0, stream>>>(
            Tcat, 600, 600, nullptr, nullptr, fc1Wt, 608, fc1_b, Tv, 400, MT, 400);
        gemm_mfma<0, 1, 0><<<dim3(4, gE), 256, 0, stream>>>(
            Ecat, 600, 600, nullptr, nullptr, fc2Wt, 608, fc2_b, Ev, 400, ME, 400);
        // 5. pooling score: P = tanh(x @ W1 + b1)  (Pt/Pe overlay Eproj)
        gemm_mfma<0, 1, 1><<<dim3(2, gT), 256, 0, stream>>>(
            Tv, 400, 400, nullptr, nullptr, aptWt, 416, apt_b1, Pt, 200, MT, 200);
        gemm_mfma<0, 1, 1><<<dim3(2, gE), 256, 0, stream>>>(
            Ev, 400, 400, nullptr, nullptr, apeWt, 416, ape_b1, Pe, 200, ME, 200);
        // 6. pooling finalize -> tvec/evec slices
        pool_finalize<30><<<C, 256, 0, stream>>>(Pt, Tv, apt_w2, tvec + (long long)c0 * 400);
        pool_finalize<10><<<C, 256, 0, stream>>>(Pe, Ev, ape_w2, evec + (long long)c0 * 400);
    }
    // 7. fc3 on [tvec | evec | vert_vec]
    gemm_fc3<<<dim3(4, BATCH / 64), 256, 0, stream>>>(tvec, evec, vert_table, vert_ids, fc3_W, fc3_b, outp);
}

// Round 4
// 2179.631 us; speedup vs baseline: 2.2933x; 1.3276x over previous
//
#include <hip/hip_runtime.h>
#include <hip/hip_bf16.h>

typedef unsigned short u16b;
typedef __attribute__((ext_vector_type(8))) short bf16x8;
typedef __attribute__((ext_vector_type(4))) float f32x4;

__device__ __forceinline__ float b2f(u16b u) { return __uint_as_float(((unsigned)u) << 16); }
__device__ __forceinline__ u16b f2b(float f) {
    unsigned u = __float_as_uint(f);
    unsigned r = u + 0x7fffu + ((u >> 16) & 1u);
    return (u16b)(r >> 16);
}
__device__ __forceinline__ int pk2(float a, float b) {
    return (int)f2b(a) | ((int)f2b(b) << 16);
}

// async 16B global -> LDS (dest = wave-uniform base + lane*16)
__device__ __forceinline__ void async16(const u16b* g, u16b* l) {
    __builtin_amdgcn_global_load_lds(
        (const __attribute__((address_space(1))) unsigned int*)g,
        (__attribute__((address_space(3))) unsigned int*)l,
        16, 0, 0);
}

#define BATCH 4096
#define NPROJ 1920   /* proj out stride; cols 0..1799 valid */

// ================= weight packs (f32 -> bf16 transposed, zero-pad K->Kp, N->Npad) =================
__global__ void pack_wcatT(const float* __restrict__ WQ, const float* __restrict__ WK,
                           const float* __restrict__ WV, const float* __restrict__ WQ2,
                           const float* __restrict__ WK2, const float* __restrict__ WV2,
                           u16b* __restrict__ Wt) {   // [1920][320]
    int idx = blockIdx.x * 256 + threadIdx.x;
    if (idx >= 1920 * 320) return;
    int n = idx / 320, k = idx % 320;
    float v = 0.0f;
    if (k < 300 && n < 1800) {
        if      (n < 400)  v = WQ [k * 400 + n];
        else if (n < 800)  v = WK [k * 400 + (n - 400)];
        else if (n < 1200) v = WV [k * 400 + (n - 800)];
        else if (n < 1400) v = WQ2[k * 200 + (n - 1200)];
        else if (n < 1600) v = WK2[k * 200 + (n - 1400)];
        else               v = WV2[k * 200 + (n - 1600)];
    }
    Wt[idx] = f2b(v);
}

__global__ void pack_wt(const float* __restrict__ W, u16b* __restrict__ Wt,
                        int K, int N, int Kp, int Npad) {
    int idx = blockIdx.x * 256 + threadIdx.x;
    if (idx >= Npad * Kp) return;
    int n = idx / Kp, k = idx % Kp;
    Wt[idx] = f2b((k < K && n < N) ? W[k * N + n] : 0.0f);
}

// ================= gather + f32->bf16 convert: Abuf[M][320] = table[ids[m]][0..299] =================
__global__ void gather_bf16(const int* __restrict__ ids, const float* __restrict__ table,
                            u16b* __restrict__ Abuf, int nrows) {
    int idx = blockIdx.x * 256 + threadIdx.x;
    if (idx >= nrows * 40) return;
    int row = idx / 40, c = idx % 40;
    int k = c * 8;
    const float* src = table + (long long)ids[row] * 300;
    int4 v;
    if (k + 8 <= 300) {
        float4 f0 = *(const float4*)(src + k);
        float4 f1 = *(const float4*)(src + k + 4);
        v.x = pk2(f0.x, f0.y); v.y = pk2(f0.z, f0.w);
        v.z = pk2(f1.x, f1.y); v.w = pk2(f1.z, f1.w);
    } else if (k < 300) {
        float f[8];
        #pragma unroll
        for (int i = 0; i < 8; i++) f[i] = (k + i < 300) ? src[k + i] : 0.0f;
        v.x = pk2(f[0], f[1]); v.y = pk2(f[2], f[3]);
        v.z = pk2(f[4], f[5]); v.w = pk2(f[6], f[7]);
    } else {
        v.x = v.y = v.z = v.w = 0;
    }
    *(int4*)(Abuf + (long long)row * 320 + k) = v;
}

// ================= MFMA GEMM, m97-style =================
// Out[M,N](bf16) = A[M,lda](bf16) @ Wt[Npad][ldwt]^T + bias (opt tanh)
// Requirements: M%128==0; lda,ldwt rows 16B-aligned; Wt zero-padded so any
// A k-pad garbage multiplies zero; grid=(ceil(N/128), M/128); 256 thr = 4 waves.
// Staging: global_load_lds 16B, XOR chunk swizzle slot = chunk ^ ((row>>1)&3).
template<int HAS_BIAS, int DO_TANH>
__global__ __launch_bounds__(256) void gemm_mfma2(
        const u16b* __restrict__ A, long long lda,
        const u16b* __restrict__ Wt, int ldwt,
        const float* __restrict__ Bias,
        u16b* __restrict__ Out, long long ldo,
        int kiters, int N) {
    __shared__ __align__(16) u16b As[128 * 32];
    __shared__ __align__(16) u16b Bs[128 * 32];
    const int t = threadIdx.x, lane = t & 63, w = t >> 6;
    const int wm = w & 1, wn = w >> 1;
    const long long m0 = (long long)blockIdx.y * 128;
    const int n0 = blockIdx.x * 128;

    // staging source addresses: wave w covers rows [w*32, w*32+32) of As and Bs,
    // two 16-row issues each. lane -> (row_in_seg = lane>>2, slot = lane&3),
    // source chunk = slot ^ ((row>>1)&3)  (row>>1 &3 invariant under +16)
    const int r0 = w * 32 + (lane >> 2);
    const int r1 = r0 + 16;
    const int cch = ((lane & 3) ^ ((r0 >> 1) & 3)) * 8;
    const u16b* gA0 = A + (m0 + r0) * lda + cch;
    const u16b* gA1 = A + (m0 + r1) * lda + cch;
    const u16b* gB0 = Wt + (long long)(n0 + r0) * ldwt + cch;
    const u16b* gB1 = Wt + (long long)(n0 + r1) * ldwt + cch;
    u16b* lA0 = &As[(w * 32) * 32];
    u16b* lA1 = &As[(w * 32 + 16) * 32];
    u16b* lB0 = &Bs[(w * 32) * 32];
    u16b* lB1 = &Bs[(w * 32 + 16) * 32];

    // fragment read offsets (slot-swizzled)
    const int lr = lane & 15;
    const int kq8 = lane >> 4;                       // 8-elem k-group 0..3
    const int slot = (kq8 ^ ((lr >> 1) & 3)) * 8;
    const u16b* aBase = &As[(wm * 64 + lr) * 32 + slot];
    const u16b* bBase = &Bs[(wn * 64 + lr) * 32 + slot];

    f32x4 acc[4][4];
    const f32x4 zf = {0.f, 0.f, 0.f, 0.f};
    #pragma unroll
    for (int mi = 0; mi < 4; mi++)
        #pragma unroll
        for (int ni = 0; ni < 4; ni++) acc[mi][ni] = zf;

    for (int it = 0; it < kiters; ++it) {
        async16(gA0, lA0); async16(gA1, lA1);
        async16(gB0, lB0); async16(gB1, lB1);
        gA0 += 32; gA1 += 32; gB0 += 32; gB1 += 32;
        __syncthreads();
        bf16x8 af[4], bf[4];
        #pragma unroll
        for (int mi = 0; mi < 4; mi++) af[mi] = *(const bf16x8*)(aBase + mi * 16 * 32);
        #pragma unroll
        for (int ni = 0; ni < 4; ni++) bf[ni] = *(const bf16x8*)(bBase + ni * 16 * 32);
        #pragma unroll
        for (int mi = 0; mi < 4; mi++)
            #pragma unroll
            for (int ni = 0; ni < 4; ni++)
                acc[mi][ni] = __builtin_amdgcn_mfma_f32_16x16x32_bf16(af[mi], bf[ni], acc[mi][ni], 0, 0, 0);
        __syncthreads();
    }

    // epilogue: C/D layout col=lane&15, row=(lane>>4)*4+r ; M%128==0 -> no row predicate
    const int cl = lane & 15;
    const int rb = (lane >> 4) * 4;
    #pragma unroll
    for (int ni = 0; ni < 4; ni++) {
        const int col = n0 + wn * 64 + ni * 16 + cl;
        if (col >= N) continue;
        const float bias = HAS_BIAS ? Bias[col] : 0.0f;
        #pragma unroll
        for (int mi = 0; mi < 4; mi++) {
            #pragma unroll
            for (int r = 0; r < 4; r++) {
                const long long row = m0 + wm * 64 + mi * 16 + rb + r;
                float v = acc[mi][ni][r] + bias;
                if (DO_TANH) v = tanhf(v);
                Out[row * ldo + col] = f2b(v);
            }
        }
    }
}

// ---------------- fc3 GEMM: out[4096,400](f32) = [tvec|evec|vert] @ fc3_W + b ----------------
__global__ __launch_bounds__(256) void gemm_fc3(const float* __restrict__ tvec,
                                                const float* __restrict__ evec,
                                                const float* __restrict__ vtab,
                                                const int* __restrict__ vids,
                                                const float* __restrict__ W,
                                                const float* __restrict__ Bias,
                                                float* __restrict__ Out) {
    __shared__ float As[20][64];
    __shared__ float Bs[20][128];
    __shared__ int svid[64];
    const int t  = threadIdx.x;
    const int n0 = blockIdx.x * 128;
    const int m0 = blockIdx.y * 64;
    if (t < 64) svid[t] = vids[m0 + t];
    __syncthreads();
    const int r = t >> 2, k0 = (t & 3) * 5;
    const int bn = t & 127, bks = t >> 7;
    const int ty = t >> 4, tx = t & 15;
    float acc[4][8] = {};
    const int rr = m0 + r;
    for (int ks = 0; ks < 1000; ks += 20) {
        float av[5];
        #pragma unroll
        for (int i = 0; i < 5; i++) {
            int k = ks + k0 + i;
            float a;
            if (k < 400)      a = tvec[rr * 400 + k];
            else if (k < 800) a = evec[rr * 400 + (k - 400)];
            else              a = vtab[svid[r] * 200 + (k - 800)];
            av[i] = a;
        }
        float bv[10];
        const int nn = n0 + bn;
        #pragma unroll
        for (int i = 0; i < 10; i++)
            bv[i] = (nn < 400) ? W[(ks + i * 2 + bks) * 400 + nn] : 0.0f;
        __syncthreads();
        #pragma unroll
        for (int i = 0; i < 5; i++) As[k0 + i][r] = av[i];
        #pragma unroll
        for (int i = 0; i < 10; i++) Bs[i * 2 + bks][bn] = bv[i];
        __syncthreads();
        #pragma unroll
        for (int kk = 0; kk < 20; kk++) {
            const float4 a4  = *(const float4*)(&As[kk][ty * 4]);
            const float4 b4a = *(const float4*)(&Bs[kk][tx * 4]);
            const float4 b4b = *(const float4*)(&Bs[kk][tx * 4 + 64]);
            const float aa[4] = {a4.x, a4.y, a4.z, a4.w};
            const float bb[8] = {b4a.x, b4a.y, b4a.z, b4a.w, b4b.x, b4b.y, b4b.z, b4b.w};
            #pragma unroll
            for (int i = 0; i < 4; i++)
                #pragma unroll
                for (int j = 0; j < 8; j++) acc[i][j] = fmaf(aa[i], bb[j], acc[i][j]);
        }
    }
    #pragma unroll
    for (int i = 0; i < 4; i++) {
        long long orow = (long long)(m0 + ty * 4 + i) * 400;
        #pragma unroll
        for (int j = 0; j < 8; j++) {
            int nn = n0 + ((j < 4) ? (tx * 4 + j) : (64 + tx * 4 + j - 4));
            if (nn < 400) Out[orow + nn] = acc[i][j] + Bias[nn];
        }
    }
}

// ---------------- title attention: self MHA(20,20) + co MHA(5,40) -> Tcat[C,30,608] ----------------
// Tproj row layout: [Q1:0..399 | K1:400..799 | V1:800..1199 | Q2:1200..1399 | K2:1400..1599 | V2:1600..1799]
__global__ __launch_bounds__(256) void attn_title(const u16b* __restrict__ Tproj,
                                                  const u16b* __restrict__ Eproj,
                                                  u16b* __restrict__ Tcat) {
    __shared__ u16b sm[24000];
    const int b = blockIdx.x, t = threadIdx.x;
    for (int idx = t; idx < 12000; idx += 256) {
        int i = idx / 400, c = idx % 400;
        long long base = (long long)(b * 30 + i) * NPROJ;
        sm[idx]         = Tproj[base + 400 + c];
        sm[12000 + idx] = Tproj[base + 800 + c];
    }
    __syncthreads();
    const float scale1 = 0.22360679774997896f;
    for (int row = t; row < 600; row += 256) {
        int h = row / 30, i = row % 30;
        float q[20];
        const u16b* qrow = Tproj + (long long)(b * 30 + i) * NPROJ + h * 20;
        #pragma unroll
        for (int c = 0; c < 20; c++) q[c] = b2f(qrow[c]);
        float s[30];
        float mx = -1e30f;
        #pragma unroll
        for (int j = 0; j < 30; j++) {
            float a = 0.0f;
            #pragma unroll
            for (int c = 0; c < 20; c++) a += q[c] * b2f(sm[j * 400 + h * 20 + c]);
            s[j] = a * scale1;
            mx = fmaxf(mx, s[j]);
        }
        float sum = 0.0f;
        #pragma unroll
        for (int j = 0; j < 30; j++) { s[j] = __expf(s[j] - mx); sum += s[j]; }
        float inv = 1.0f / sum;
        #pragma unroll
        for (int c = 0; c < 20; c++) {
            float o = 0.0f;
            #pragma unroll
            for (int j = 0; j < 30; j++) o += s[j] * b2f(sm[12000 + j * 400 + h * 20 + c]);
            Tcat[(long long)(b * 30 + i) * 608 + h * 20 + c] = f2b(o * inv);
        }
    }
    __syncthreads();
    for (int idx = t; idx < 2000; idx += 256) {
        int j = idx / 200, c = idx % 200;
        long long base = (long long)(b * 10 + j) * NPROJ;
        sm[idx]        = Eproj[base + 1400 + c];
        sm[2000 + idx] = Eproj[base + 1600 + c];
    }
    __syncthreads();
    const float scale2 = 0.15811388300841897f;
    if (t < 150) {
        int h = t / 30, i = t % 30;
        float q[40];
        const u16b* qrow = Tproj + (long long)(b * 30 + i) * NPROJ + 1200 + h * 40;
        #pragma unroll
        for (int c = 0; c < 40; c++) q[c] = b2f(qrow[c]);
        float s[10];
        float mx = -1e30f;
        #pragma unroll
        for (int j = 0; j < 10; j++) {
            float a = 0.0f;
            #pragma unroll
            for (int c = 0; c < 40; c++) a += q[c] * b2f(sm[j * 200 + h * 40 + c]);
            s[j] = a * scale2;
            mx = fmaxf(mx, s[j]);
        }
        float sum = 0.0f;
        #pragma unroll
        for (int j = 0; j < 10; j++) { s[j] = __expf(s[j] - mx); sum += s[j]; }
        float inv = 1.0f / sum;
        #pragma unroll
        for (int c = 0; c < 40; c++) {
            float o = 0.0f;
            #pragma unroll
            for (int j = 0; j < 10; j++) o += s[j] * b2f(sm[2000 + j * 200 + h * 40 + c]);
            Tcat[(long long)(b * 30 + i) * 608 + 400 + h * 40 + c] = f2b(o * inv);
        }
    }
}

// ---------------- entity attention -> Ecat[C,10,608] ----------------
__global__ __launch_bounds__(256) void attn_entity(const u16b* __restrict__ Tproj,
                                                   const u16b* __restrict__ Eproj,
                                                   u16b* __restrict__ Ecat) {
    __shared__ u16b sm[12000];
    const int b = blockIdx.x, t = threadIdx.x;
    for (int idx = t; idx < 4000; idx += 256) {
        int i = idx / 400, c = idx % 400;
        long long base = (long long)(b * 10 + i) * NPROJ;
        sm[idx]        = Eproj[base + 400 + c];
        sm[4000 + idx] = Eproj[base + 800 + c];
    }
    __syncthreads();
    const float scale1 = 0.22360679774997896f;
    if (t < 200) {
        int h = t / 10, i = t % 10;
        float q[20];
        const u16b* qrow = Eproj + (long long)(b * 10 + i) * NPROJ + h * 20;
        #pragma unroll
        for (int c = 0; c < 20; c++) q[c] = b2f(qrow[c]);
        float s[10];
        float mx = -1e30f;
        #pragma unroll
        for (int j = 0; j < 10; j++) {
            float a = 0.0f;
            #pragma unroll
            for (int c = 0; c < 20; c++) a += q[c] * b2f(sm[j * 400 + h * 20 + c]);
            s[j] = a * scale1;
            mx = fmaxf(mx, s[j]);
        }
        float sum = 0.0f;
        #pragma unroll
        for (int j = 0; j < 10; j++) { s[j] = __expf(s[j] - mx); sum += s[j]; }
        float inv = 1.0f / sum;
        #pragma unroll
        for (int c = 0; c < 20; c++) {
            float o = 0.0f;
            #pragma unroll
            for (int j = 0; j < 10; j++) o += s[j] * b2f(sm[4000 + j * 400 + h * 20 + c]);
            Ecat[(long long)(b * 10 + i) * 608 + h * 20 + c] = f2b(o * inv);
        }
    }
    __syncthreads();
    for (int idx = t; idx < 6000; idx += 256) {
        int j = idx / 200, c = idx % 200;
        long long base = (long long)(b * 30 + j) * NPROJ;
        sm[idx]        = Tproj[base + 1400 + c];
        sm[6000 + idx] = Tproj[base + 1600 + c];
    }
    __syncthreads();
    const float scale2 = 0.15811388300841897f;
    if (t < 50) {
        int h = t / 10, i = t % 10;
        float q[40];
        const u16b* qrow = Eproj + (long long)(b * 10 + i) * NPROJ + 1200 + h * 40;
        #pragma unroll
        for (int c = 0; c < 40; c++) q[c] = b2f(qrow[c]);
        float s[30];
        float mx = -1e30f;
        #pragma unroll
        for (int j = 0; j < 30; j++) {
            float a = 0.0f;
            #pragma unroll
            for (int c = 0; c < 40; c++) a += q[c] * b2f(sm[j * 200 + h * 40 + c]);
            s[j] = a * scale2;
            mx = fmaxf(mx, s[j]);
        }
        float sum = 0.0f;
        #pragma unroll
        for (int j = 0; j < 30; j++) { s[j] = __expf(s[j] - mx); sum += s[j]; }
        float inv = 1.0f / sum;
        #pragma unroll
        for (int c = 0; c < 40; c++) {
            float o = 0.0f;
            #pragma unroll
            for (int j = 0; j < 30; j++) o += s[j] * b2f(sm[6000 + j * 200 + h * 40 + c]);
            Ecat[(long long)(b * 10 + i) * 608 + 400 + h * 40 + c] = f2b(o * inv);
        }
    }
}

// ---------------- attention pooling finalize ----------------
template <int L>
__global__ __launch_bounds__(256) void pool_finalize(const u16b* __restrict__ P,
                                                     const u16b* __restrict__ Vv,
                                                     const float* __restrict__ w2,
                                                     float* __restrict__ outv) {
    __shared__ float sred[L][8];
    __shared__ float sa[L];
    const int b = blockIdx.x, t = threadIdx.x;
    const int i = t / 8, u = t % 8;
    if (i < L) {
        float p = 0.0f;
        const u16b* Pr = P + (long long)(b * L + i) * 200 + u * 25;
        const float* wr = w2 + u * 25;
        #pragma unroll
        for (int c = 0; c < 25; c++) p += b2f(Pr[c]) * wr[c];
        sred[i][u] = p;
    }
    __syncthreads();
    if (t == 0) {
        float s[L];
        float mx = -1e30f;
        for (int ii = 0; ii < L; ii++) {
            float v = 0.0f;
            for (int uu = 0; uu < 8; uu++) v += sred[ii][uu];
            s[ii] = v;
            mx = fmaxf(mx, v);
        }
        float sum = 0.0f;
        for (int ii = 0; ii < L; ii++) { s[ii] = __expf(s[ii] - mx); sum += s[ii]; }
        float inv = 1.0f / sum;
        for (int ii = 0; ii < L; ii++) sa[ii] = s[ii] * inv;
    }
    __syncthreads();
    for (int f = t; f < 400; f += 256) {
        float o = 0.0f;
        #pragma unroll
        for (int ii = 0; ii < L; ii++) o += sa[ii] * b2f(Vv[(long long)(b * L + ii) * 400 + f]);
        outv[(long long)b * 400 + f] = o;
    }
}

extern "C" void kernel_launch(void* const* d_in, const int* in_sizes, int n_in,
                              void* d_out, int out_size, void* d_ws, size_t ws_size,
                              hipStream_t stream) {
    const int*   title_ids  = (const int*)d_in[0];
    const int*   vert_ids   = (const int*)d_in[1];
    const int*   entity_ids = (const int*)d_in[2];
    const float* word_table = (const float*)d_in[3];
    const float* vert_table = (const float*)d_in[4];
    const float* entity_table = (const float*)d_in[5];
    const float* WQ  = (const float*)d_in[6];
    const float* WK  = (const float*)d_in[7];
    const float* WV  = (const float*)d_in[8];
    const float* WQ2 = (const float*)d_in[9];
    const float* WK2 = (const float*)d_in[10];
    const float* WV2 = (const float*)d_in[11];
    const float* fc1_W = (const float*)d_in[12];
    const float* fc1_b = (const float*)d_in[13];
    const float* fc2_W = (const float*)d_in[14];
    const float* fc2_b = (const float*)d_in[15];
    const float* apt_W1 = (const float*)d_in[16];
    const float* apt_b1 = (const float*)d_in[17];
    const float* apt_w2 = (const float*)d_in[18];
    const float* ape_W1 = (const float*)d_in[19];
    const float* ape_b1 = (const float*)d_in[20];
    const float* ape_w2 = (const float*)d_in[21];
    const float* fc3_W = (const float*)d_in[22];
    const float* fc3_b = (const float*)d_in[23];

    // fixed region: padded bf16 weights + tvec/evec (f32, full batch)
    const long long OFF_WCATT = 0;                               // 1920*320*2 = 1,228,800
    const long long OFF_FC1WT = 1228800ll;                       // 512*608*2  =   622,592
    const long long OFF_FC2WT = OFF_FC1WT + 622592ll;
    const long long OFF_APTWT = OFF_FC2WT + 622592ll;            // 256*416*2  =   212,992
    const long long OFF_APEWT = OFF_APTWT + 212992ll;
    const long long OFF_TVEC  = OFF_APEWT + 212992ll;            // 4096*400*4 = 6,553,600
    const long long OFF_EVEC  = OFF_TVEC + 6553600ll;
    const long long fixedB    = OFF_EVEC + 6553600ll;            // 16,007,168

    // per-chunk bytes: AbufT C*19200 + AbufE C*6400 + Tproj C*115200 + Eproj C*38400
    //                + Tcat C*36480 + Ecat C*12160 = C*227840
    int C = BATCH;
    while (C > 64 && fixedB + (long long)C * 227840ll > (long long)ws_size) C >>= 1;

    char* ws = (char*)d_ws;
    const long long OFF_ABUFT = fixedB;
    const long long OFF_ABUFE = OFF_ABUFT + (long long)C * 19200ll;
    const long long OFF_TPROJ = OFF_ABUFE + (long long)C * 6400ll;
    const long long OFF_EPROJ = OFF_TPROJ + (long long)C * 115200ll;
    const long long OFF_TCAT  = OFF_EPROJ + (long long)C * 38400ll;
    const long long OFF_ECAT  = OFF_TCAT  + (long long)C * 36480ll;
    // overlays (dead-region reuse within a chunk):
    const long long OFF_TV = OFF_ABUFT;                          // C*24000 <= C*25600+...
    const long long OFF_EV = OFF_ABUFT + (long long)C * 24000ll; // C*8000
    const long long OFF_PT = OFF_EPROJ;                          // C*12000 <= C*38400
    const long long OFF_PE = OFF_EPROJ + (long long)C * 12000ll; // C*4000

    u16b*  wcatT = (u16b*)(ws + OFF_WCATT);
    u16b*  fc1Wt = (u16b*)(ws + OFF_FC1WT);
    u16b*  fc2Wt = (u16b*)(ws + OFF_FC2WT);
    u16b*  aptWt = (u16b*)(ws + OFF_APTWT);
    u16b*  apeWt = (u16b*)(ws + OFF_APEWT);
    float* tvec  = (float*)(ws + OFF_TVEC);
    float* evec  = (float*)(ws + OFF_EVEC);
    u16b*  AbufT = (u16b*)(ws + OFF_ABUFT);
    u16b*  AbufE = (u16b*)(ws + OFF_ABUFE);
    u16b*  Tproj = (u16b*)(ws + OFF_TPROJ);
    u16b*  Eproj = (u16b*)(ws + OFF_EPROJ);
    u16b*  Tcat  = (u16b*)(ws + OFF_TCAT);
    u16b*  Ecat  = (u16b*)(ws + OFF_ECAT);
    u16b*  Tv    = (u16b*)(ws + OFF_TV);
    u16b*  Ev    = (u16b*)(ws + OFF_EV);
    u16b*  Pt    = (u16b*)(ws + OFF_PT);
    u16b*  Pe    = (u16b*)(ws + OFF_PE);
    float* outp  = (float*)d_out;

    // 1. pack bf16 transposed, zero-padded weights
    pack_wcatT<<<(1920 * 320 + 255) / 256, 256, 0, stream>>>(WQ, WK, WV, WQ2, WK2, WV2, wcatT);
    pack_wt<<<(512 * 608 + 255) / 256, 256, 0, stream>>>(fc1_W, fc1Wt, 600, 400, 608, 512);
    pack_wt<<<(512 * 608 + 255) / 256, 256, 0, stream>>>(fc2_W, fc2Wt, 600, 400, 608, 512);
    pack_wt<<<(256 * 416 + 255) / 256, 256, 0, stream>>>(apt_W1, aptWt, 400, 200, 416, 256);
    pack_wt<<<(256 * 416 + 255) / 256, 256, 0, stream>>>(ape_W1, apeWt, 400, 200, 416, 256);

    for (int c0 = 0; c0 < BATCH; c0 += C) {
        const int MT = C * 30, ME = C * 10;        // both multiples of 128 (C%64==0)
        // 2a. gather + convert to bf16 (once per row, kills 15x redundancy)
        gather_bf16<<<(MT * 40 + 255) / 256, 256, 0, stream>>>(
            title_ids + (long long)c0 * 30, word_table, AbufT, MT);
        gather_bf16<<<(ME * 40 + 255) / 256, 256, 0, stream>>>(
            entity_ids + (long long)c0 * 10, entity_table, AbufE, ME);
        // 2b. projections: N=1800 (15 tiles), K=320 (10 iters), out stride 1920
        gemm_mfma2<0, 0><<<dim3(15, MT / 128), 256, 0, stream>>>(
            AbufT, 320, wcatT, 320, nullptr, Tproj, NPROJ, 10, 1800);
        gemm_mfma2<0, 0><<<dim3(15, ME / 128), 256, 0, stream>>>(
            AbufE, 320, wcatT, 320, nullptr, Eproj, NPROJ, 10, 1800);
        // 3. attention (self + co) -> Tcat/Ecat stride 608 (cols 600..607 = don't-care pad)
        attn_title<<<C, 256, 0, stream>>>(Tproj, Eproj, Tcat);
        attn_entity<<<C, 256, 0, stream>>>(Tproj, Eproj, Ecat);
        // 4. fc1 / fc2: K=600->608 (19 iters), N=400
        gemm_mfma2<1, 0><<<dim3(4, MT / 128), 256, 0, stream>>>(
            Tcat, 608, fc1Wt, 608, fc1_b, Tv, 400, 19, 400);
        gemm_mfma2<1, 0><<<dim3(4, ME / 128), 256, 0, stream>>>(
            Ecat, 608, fc2Wt, 608, fc2_b, Ev, 400, 19, 400);
        // 5. pooling score: P = tanh(x @ W1 + b1), K=400->416 (13 iters), N=200
        gemm_mfma2<1, 1><<<dim3(2, MT / 128), 256, 0, stream>>>(
            Tv, 400, aptWt, 416, apt_b1, Pt, 200, 13, 200);
        gemm_mfma2<1, 1><<<dim3(2, ME / 128), 256, 0, stream>>>(
            Ev, 400, apeWt, 416, ape_b1, Pe, 200, 13, 200);
        // 6. pooling finalize -> tvec/evec slices
        pool_finalize<30><<<C, 256, 0, stream>>>(Pt, Tv, apt_w2, tvec + (long long)c0 * 400);
        pool_finalize<10><<<C, 256, 0, stream>>>(Pe, Ev, ape_w2, evec + (long long)c0 * 400);
    }
    // 7. fc3 on [tvec | evec | vert_vec]
    gemm_fc3<<<dim3(4, BATCH / 64), 256, 0, stream>>>(tvec, evec, vert_table, vert_ids, fc3_W, fc3_b, outp);
}